// Round 1
// baseline (5219.736 us; speedup 1.0000x reference)
//
#include <hip/hip_runtime.h>
#include <hip/hip_bf16.h>

#define H_DIM 2048
#define I_DIM 5632
#define E_NUM 8
#define T_NUM 2048
#define BK 32

// ---- workspace layout (bytes) ----
// [0,64)    counts[E]      (zeroed by memsetAsync)
// [64,128)  cursors[E]     (zeroed by memsetAsync)
// [128,256) offsets[E+1]
// [256, +16K)   rows_tok[4096]  : global row -> token id
// [16640,+16K)  rows_wt[4096]   : global row -> routing weight
// [33024,+16K)  tok_rows[T*2]   : token -> (expert id before assign, row after)
// [49408,+16K)  tok_wts[T*2]
// [1MB, +46.1MB) act bf16 [4096][I]
// [~47.2MB, +33.6MB) y fp32 [4096][H]
static constexpr size_t WS_COUNTS  = 0;
static constexpr size_t WS_CURSORS = 64;
static constexpr size_t WS_OFFSETS = 128;
static constexpr size_t WS_ROWTOK  = 256;
static constexpr size_t WS_ROWWT   = WS_ROWTOK + 4096 * 4;
static constexpr size_t WS_TOKROWS = WS_ROWWT + 4096 * 4;
static constexpr size_t WS_TOKWTS  = WS_TOKROWS + T_NUM * 2 * 4;
static constexpr size_t WS_ACT     = 1u << 20;
static constexpr size_t WS_Y       = WS_ACT + (size_t)4096 * I_DIM * 2;

typedef __attribute__((ext_vector_type(8))) short short8;
typedef __attribute__((ext_vector_type(4))) float f32x4;

__device__ __forceinline__ ushort f2bf(float f) {
    union { float f; unsigned int u; } v; v.f = f;
    return (ushort)((v.u + 0x8000u) >> 16);   // round-half-up in bit space (~RNE accuracy)
}

// ---------------- router: one wave per token ----------------
__global__ __launch_bounds__(256) void router_kernel(
    const float* __restrict__ x, const float* __restrict__ gw,
    int* __restrict__ counts, int* __restrict__ tok_e, float* __restrict__ tok_w)
{
    int wid = threadIdx.x >> 6, lane = threadIdx.x & 63;
    int t = blockIdx.x * 4 + wid;
    const float* xr = x + (size_t)t * H_DIM;
    float acc[E_NUM];
#pragma unroll
    for (int e = 0; e < E_NUM; ++e) acc[e] = 0.f;
    for (int h = lane; h < H_DIM; h += 64) {
        float xv = xr[h];
#pragma unroll
        for (int e = 0; e < E_NUM; ++e) acc[e] += xv * gw[e * H_DIM + h];
    }
#pragma unroll
    for (int e = 0; e < E_NUM; ++e)
        for (int o = 32; o > 0; o >>= 1) acc[e] += __shfl_down(acc[e], o);
    if (lane == 0) {
        int e0 = 0; float l0 = acc[0];
#pragma unroll
        for (int e = 1; e < E_NUM; ++e) if (acc[e] > l0) { l0 = acc[e]; e0 = e; }
        int e1 = -1; float l1 = -1e30f;
#pragma unroll
        for (int e = 0; e < E_NUM; ++e) if (e != e0 && acc[e] > l1) { l1 = acc[e]; e1 = e; }
        float p1 = __expf(l1 - l0);
        float inv = 1.f / (1.f + p1);
        atomicAdd(&counts[e0], 1);
        atomicAdd(&counts[e1], 1);
        tok_e[2 * t] = e0; tok_e[2 * t + 1] = e1;
        tok_w[2 * t] = inv; tok_w[2 * t + 1] = p1 * inv;
    }
}

__global__ void scan_kernel(const int* __restrict__ counts, int* __restrict__ offsets) {
    if (threadIdx.x == 0) {
        int s = 0;
#pragma unroll
        for (int e = 0; e < E_NUM; ++e) { offsets[e] = s; s += counts[e]; }
        offsets[E_NUM] = s;
    }
}

__global__ __launch_bounds__(256) void assign_kernel(
    const int* __restrict__ offsets, int* __restrict__ cursors,
    int* __restrict__ tok_rows /* in: expert ids; out: rows */,
    const float* __restrict__ tok_w,
    int* __restrict__ rows_tok, float* __restrict__ rows_wt)
{
    int t = blockIdx.x * 256 + threadIdx.x;
#pragma unroll
    for (int j = 0; j < 2; ++j) {
        int e = tok_rows[2 * t + j];
        int slot = atomicAdd(&cursors[e], 1);
        int row = offsets[e] + slot;
        rows_tok[row] = t;
        rows_wt[row] = tok_w[2 * t + j];
        tok_rows[2 * t + j] = row;
    }
}

// ---------------- gemm1: fused gate+up, SiLU epilogue, act bf16 out ----------------
// C[r, i] over rows of expert e; A = gathered x rows (fp32->bf16), B = w_gate/w_up rows (NT gemm)
__global__ __launch_bounds__(256) void gemm1_kernel(
    const float* __restrict__ x, const float* __restrict__ w_gate, const float* __restrict__ w_up,
    const int* __restrict__ offsets, const int* __restrict__ rows_tok, ushort* __restrict__ act)
{
    const int e = blockIdx.z;
    const int off = offsets[e];
    const int ne = offsets[e + 1] - off;
    const int row0 = blockIdx.x * 128;
    if (row0 >= ne) return;
    const int col0 = blockIdx.y * 128;

    __shared__ __align__(16) ushort sA[128 * 56];
    __shared__ __align__(16) ushort sBg[128 * 56];
    __shared__ __align__(16) ushort sBu[128 * 56];

    const int tid = threadIdx.x;
    const int lane = tid & 63, wid = tid >> 6;
    const int wm = wid & 1, wn = wid >> 1;
    const int quad = lane >> 4, l16 = lane & 15;
    const int srow = tid >> 3, skc = tid & 7;   // staging: 32 rows x 8 float4-chunks

    int tokid[4];
#pragma unroll
    for (int rb = 0; rb < 4; ++rb) {
        int gr = row0 + rb * 32 + srow;
        tokid[rb] = (gr < ne) ? rows_tok[off + gr] : -1;
    }

    const float* wg = w_gate + (size_t)e * I_DIM * H_DIM;
    const float* wu = w_up   + (size_t)e * I_DIM * H_DIM;

    f32x4 accg[4][4], accu[4][4];
#pragma unroll
    for (int i = 0; i < 4; ++i)
#pragma unroll
        for (int j = 0; j < 4; ++j) { accg[i][j] = (f32x4){0.f,0.f,0.f,0.f}; accu[i][j] = (f32x4){0.f,0.f,0.f,0.f}; }

    for (int kk = 0; kk < H_DIM; kk += BK) {
        __syncthreads();
#pragma unroll
        for (int rb = 0; rb < 4; ++rb) {
            int r = rb * 32 + srow;
            ushort4 w;
            if (tokid[rb] >= 0) {
                const float4 v = *(const float4*)(x + (size_t)tokid[rb] * H_DIM + kk + skc * 4);
                w = make_ushort4(f2bf(v.x), f2bf(v.y), f2bf(v.z), f2bf(v.w));
            } else w = make_ushort4(0, 0, 0, 0);
            *(ushort4*)&sA[r * 56 + skc * 4] = w;
        }
#pragma unroll
        for (int rb = 0; rb < 4; ++rb) {
            int r = rb * 32 + srow;
            size_t go = (size_t)(col0 + r) * H_DIM + kk + skc * 4;
            const float4 vg = *(const float4*)(wg + go);
            const float4 vu = *(const float4*)(wu + go);
            *(ushort4*)&sBg[r * 56 + skc * 4] = make_ushort4(f2bf(vg.x), f2bf(vg.y), f2bf(vg.z), f2bf(vg.w));
            *(ushort4*)&sBu[r * 56 + skc * 4] = make_ushort4(f2bf(vu.x), f2bf(vu.y), f2bf(vu.z), f2bf(vu.w));
        }
        __syncthreads();

        short8 af[4], bgf[4], buf_[4];
#pragma unroll
        for (int i = 0; i < 4; ++i) {
            af[i]   = *(const short8*)&sA [(wm * 64 + i * 16 + l16) * 56 + quad * 8];
            bgf[i]  = *(const short8*)&sBg[(wn * 64 + i * 16 + l16) * 56 + quad * 8];
            buf_[i] = *(const short8*)&sBu[(wn * 64 + i * 16 + l16) * 56 + quad * 8];
        }
#pragma unroll
        for (int i = 0; i < 4; ++i)
#pragma unroll
            for (int j = 0; j < 4; ++j) {
                accg[i][j] = __builtin_amdgcn_mfma_f32_16x16x32_bf16(af[i], bgf[j], accg[i][j], 0, 0, 0);
                accu[i][j] = __builtin_amdgcn_mfma_f32_16x16x32_bf16(af[i], buf_[j], accu[i][j], 0, 0, 0);
            }
    }

#pragma unroll
    for (int i = 0; i < 4; ++i) {
#pragma unroll
        for (int reg = 0; reg < 4; ++reg) {
            int lr = wm * 64 + i * 16 + quad * 4 + reg;   // C/D: row=(lane>>4)*4+reg
            int r = row0 + lr;
            if (r < ne) {
                size_t base = (size_t)(off + r) * I_DIM + col0 + wn * 64;
#pragma unroll
                for (int j = 0; j < 4; ++j) {
                    float g = accg[i][j][reg], u = accu[i][j][reg];
                    float a = g * (1.f / (1.f + __expf(-g))) * u;   // silu(g)*u
                    act[base + j * 16 + l16] = f2bf(a);
                }
            }
        }
    }
}

// ---------------- gemm2: y[r,h] = wt[r] * (act[r,:] @ w_down[e,h,:]) ----------------
__global__ __launch_bounds__(256) void gemm2_kernel(
    const ushort* __restrict__ act, const float* __restrict__ w_down,
    const int* __restrict__ offsets, const float* __restrict__ rows_wt, float* __restrict__ y)
{
    const int e = blockIdx.z;
    const int off = offsets[e];
    const int ne = offsets[e + 1] - off;
    const int row0 = blockIdx.x * 128;
    if (row0 >= ne) return;
    const int col0 = blockIdx.y * 128;

    __shared__ __align__(16) ushort sA[128 * 56];
    __shared__ __align__(16) ushort sB[128 * 56];
    __shared__ float sWt[128];

    const int tid = threadIdx.x;
    const int lane = tid & 63, wid = tid >> 6;
    const int wm = wid & 1, wn = wid >> 1;
    const int quad = lane >> 4, l16 = lane & 15;

    if (tid < 128) sWt[tid] = (row0 + tid < ne) ? rows_wt[off + row0 + tid] : 0.f;

    const float* wd = w_down + (size_t)e * H_DIM * I_DIM;

    f32x4 acc[4][4];
#pragma unroll
    for (int i = 0; i < 4; ++i)
#pragma unroll
        for (int j = 0; j < 4; ++j) acc[i][j] = (f32x4){0.f,0.f,0.f,0.f};

    const int arow = tid >> 2, akc = tid & 3;  // A: 64 rows x 4 chunks (8 bf16 ea)
    const int brow = tid >> 3, bkc = tid & 7;  // B: 32 rows x 8 float4-chunks

    for (int kk = 0; kk < I_DIM; kk += BK) {
        __syncthreads();
#pragma unroll
        for (int rb = 0; rb < 2; ++rb) {
            int r = rb * 64 + arow;
            int gr = row0 + r;
            uint4 v = make_uint4(0, 0, 0, 0);
            if (gr < ne) v = *(const uint4*)(act + (size_t)(off + gr) * I_DIM + kk + akc * 8);
            *(uint4*)&sA[r * 56 + akc * 8] = v;
        }
#pragma unroll
        for (int rb = 0; rb < 4; ++rb) {
            int r = rb * 32 + brow;
            const float4 v = *(const float4*)(wd + (size_t)(col0 + r) * I_DIM + kk + bkc * 4);
            *(ushort4*)&sB[r * 56 + bkc * 4] = make_ushort4(f2bf(v.x), f2bf(v.y), f2bf(v.z), f2bf(v.w));
        }
        __syncthreads();

        short8 af[4], bf[4];
#pragma unroll
        for (int i = 0; i < 4; ++i) {
            af[i] = *(const short8*)&sA[(wm * 64 + i * 16 + l16) * 56 + quad * 8];
            bf[i] = *(const short8*)&sB[(wn * 64 + i * 16 + l16) * 56 + quad * 8];
        }
#pragma unroll
        for (int i = 0; i < 4; ++i)
#pragma unroll
            for (int j = 0; j < 4; ++j)
                acc[i][j] = __builtin_amdgcn_mfma_f32_16x16x32_bf16(af[i], bf[j], acc[i][j], 0, 0, 0);
    }

#pragma unroll
    for (int i = 0; i < 4; ++i) {
#pragma unroll
        for (int reg = 0; reg < 4; ++reg) {
            int lr = wm * 64 + i * 16 + quad * 4 + reg;
            int r = row0 + lr;
            if (r < ne) {
                float wt = sWt[lr];
                size_t base = (size_t)(off + r) * H_DIM + col0 + wn * 64;
#pragma unroll
                for (int j = 0; j < 4; ++j)
                    y[base + j * 16 + l16] = wt * acc[i][j][reg];
            }
        }
    }
}

// ---------------- combine: out[t,:] = y[r0,:] + y[r1,:] (weights already applied) ----------------
__global__ __launch_bounds__(256) void combine_kernel(
    const float* __restrict__ y, const int* __restrict__ tok_rows, float* __restrict__ out)
{
    int idx = blockIdx.x * 256 + threadIdx.x;   // T*H/4 total
    int t = idx >> 9;           // H/4 = 512 float4 per row
    int c = idx & 511;
    int r0 = tok_rows[2 * t], r1 = tok_rows[2 * t + 1];
    const float4 a = *(const float4*)(y + (size_t)r0 * H_DIM + c * 4);
    const float4 b = *(const float4*)(y + (size_t)r1 * H_DIM + c * 4);
    float4 o; o.x = a.x + b.x; o.y = a.y + b.y; o.z = a.z + b.z; o.w = a.w + b.w;
    *(float4*)(out + (size_t)t * H_DIM + c * 4) = o;
}

extern "C" void kernel_launch(void* const* d_in, const int* in_sizes, int n_in,
                              void* d_out, int out_size, void* d_ws, size_t ws_size,
                              hipStream_t stream) {
    const float* x      = (const float*)d_in[0];
    const float* gate_w = (const float*)d_in[1];
    const float* w_gate = (const float*)d_in[2];
    const float* w_up   = (const float*)d_in[3];
    const float* w_down = (const float*)d_in[4];
    float* out = (float*)d_out;
    char* ws = (char*)d_ws;

    int*    counts   = (int*)(ws + WS_COUNTS);
    int*    cursors  = (int*)(ws + WS_CURSORS);
    int*    offsets  = (int*)(ws + WS_OFFSETS);
    int*    rows_tok = (int*)(ws + WS_ROWTOK);
    float*  rows_wt  = (float*)(ws + WS_ROWWT);
    int*    tok_rows = (int*)(ws + WS_TOKROWS);
    float*  tok_wts  = (float*)(ws + WS_TOKWTS);
    ushort* act      = (ushort*)(ws + WS_ACT);
    float*  y        = (float*)(ws + WS_Y);

    hipMemsetAsync(ws, 0, 256, stream);
    router_kernel<<<T_NUM / 4, 256, 0, stream>>>(x, gate_w, counts, tok_rows, tok_wts);
    scan_kernel<<<1, 64, 0, stream>>>(counts, offsets);
    assign_kernel<<<T_NUM / 256, 256, 0, stream>>>(offsets, cursors, tok_rows, tok_wts, rows_tok, rows_wt);
    gemm1_kernel<<<dim3(16, I_DIM / 128, E_NUM), 256, 0, stream>>>(x, w_gate, w_up, offsets, rows_tok, act);
    gemm2_kernel<<<dim3(16, H_DIM / 128, E_NUM), 256, 0, stream>>>(act, w_down, offsets, rows_wt, y);
    combine_kernel<<<(T_NUM * H_DIM / 4) / 256, 256, 0, stream>>>(y, tok_rows, out);
}